// Round 11
// baseline (180.703 us; speedup 1.0000x reference)
//
#include <hip/hip_runtime.h>
#include <math.h>

#define NQ      512
#define DMODEL  256
#define DINNER  512
#define NH      8
#define DHEAD   64
#define SCALE   0.125f
#define PI_F    3.14159265358979323846f

// workspace layout (float offsets)
#define Q_OFF   0           // 512*512
#define KC_OFF  262144      // 512*512
#define V_OFF   524288      // 512*512
#define QW_OFF  786432      // 512*544 (per-head blocks of 68)
#define IN_OFF  1064960     // 512*512
#define PA_OFF  1327104     // 4096*8*64 partial accs
#define PM_OFF  3424256     // 4096*8 partial maxes
#define PL_OFF  3457024     // 4096*8 partial sums
// total 3489792 floats = 14.0 MB

// ---------------------------------------------------------------- K1: q/kc/v
__global__ __launch_bounds__(256) void k_proj(
    const float* __restrict__ x, const float* __restrict__ Wq,
    const float* __restrict__ Wk, const float* __restrict__ Wv,
    float* __restrict__ ws)
{
    const int z = blockIdx.z;
    const float* W = (z == 0) ? Wq : (z == 1) ? Wk : Wv;
    float* out = ws + ((z == 0) ? Q_OFF : (z == 1) ? KC_OFF : V_OFF);

    __shared__ alignas(16) float Xs[32][68];
    __shared__ alignas(16) float Bs[32][64];

    const int tx = threadIdx.x, ty = threadIdx.y;
    const int tid = ty * 16 + tx;
    const int row0 = blockIdx.y * 64, col0 = blockIdx.x * 64;

    float acc[4][4] = {};

    for (int k0 = 0; k0 < DMODEL; k0 += 32) {
        {
            const int m = tid >> 2;
            const int kk0 = (tid & 3) * 8;
            const float* src = x + (row0 + m) * DMODEL + k0 + kk0;
            float4 a0 = *(const float4*)(src);
            float4 a1 = *(const float4*)(src + 4);
            Xs[kk0 + 0][m] = a0.x; Xs[kk0 + 1][m] = a0.y;
            Xs[kk0 + 2][m] = a0.z; Xs[kk0 + 3][m] = a0.w;
            Xs[kk0 + 4][m] = a1.x; Xs[kk0 + 5][m] = a1.y;
            Xs[kk0 + 6][m] = a1.z; Xs[kk0 + 7][m] = a1.w;
        }
        {
            const int kk = tid >> 3;
            const int n0 = (tid & 7) * 8;
            const float* src = W + (k0 + kk) * DINNER + col0 + n0;
            *(float4*)&Bs[kk][n0]     = *(const float4*)(src);
            *(float4*)&Bs[kk][n0 + 4] = *(const float4*)(src + 4);
        }
        __syncthreads();
        #pragma unroll
        for (int kk = 0; kk < 32; ++kk) {
            float4 a4 = *(const float4*)&Xs[kk][ty * 4];
            float4 b4 = *(const float4*)&Bs[kk][tx * 4];
            float a[4] = {a4.x, a4.y, a4.z, a4.w};
            float b[4] = {b4.x, b4.y, b4.z, b4.w};
            #pragma unroll
            for (int ia = 0; ia < 4; ++ia)
                #pragma unroll
                for (int ib = 0; ib < 4; ++ib)
                    acc[ia][ib] += a[ia] * b[ib];
        }
        __syncthreads();
    }
    #pragma unroll
    for (int ia = 0; ia < 4; ++ia) {
        float4 o = make_float4(acc[ia][0], acc[ia][1], acc[ia][2], acc[ia][3]);
        *(float4*)&out[(row0 + ty * 4 + ia) * DINNER + col0 + tx * 4] = o;
    }
}

// ------------------------------------------------- K1b: qW, per-head layout
// qW[i*544 + h*68 + p]; p: 0..15 sin_x, 16..31 cos_x, 32..47 sin_y,
// 48..63 cos_y, 64 dx-weight, 65 dy-weight. (SCALE folded in.)
__global__ __launch_bounds__(256) void k_qw(
    const float* __restrict__ Wk, float* __restrict__ ws)
{
    const float* q = ws + Q_OFF;
    float* qW = ws + QW_OFF;
    const int h  = blockIdx.x >> 4;          // 8 heads
    const int i0 = (blockIdx.x & 15) * 32;   // 16 row-tiles of 32

    __shared__ float WrT[64][67];            // [d][r], pad 67
    __shared__ alignas(16) float Qs[32][68]; // [m][d]
    const int tid = threadIdx.x;

    for (int idx = tid; idx < 66 * 64; idx += 256) {
        int r = idx >> 6, d = idx & 63;
        WrT[d][r] = Wk[(DMODEL + r) * DINNER + h * DHEAD + d];
    }
    for (int idx = tid; idx < 32 * 16; idx += 256) {
        int m = idx >> 4, dq = (idx & 15) * 4;
        *(float4*)&Qs[m][dq] = *(const float4*)&q[(i0 + m) * DINNER + h * DHEAD + dq];
    }
    __syncthreads();

    for (int idx = tid; idx < 32 * 66; idx += 256) {
        int m = idx / 66, r = idx - m * 66;
        float acc = 0.f;
        #pragma unroll
        for (int d0 = 0; d0 < 64; d0 += 4) {
            float4 qf = *(const float4*)&Qs[m][d0];
            acc += qf.x * WrT[d0 + 0][r] + qf.y * WrT[d0 + 1][r]
                 + qf.z * WrT[d0 + 2][r] + qf.w * WrT[d0 + 3][r];
        }
        // original r: 0..15 sinx, 16..31 cosx, 32 dx, 33..48 siny, 49..64 cosy, 65 dy
        int p = (r < 32) ? r : (r == 32) ? 64 : (r < 65) ? (r - 1) : 65;
        qW[(i0 + m) * 544 + h * 68 + p] = acc * SCALE;
    }
}

// --------- fused attention v3: lane = query row; spill-safe + coalesced ----
// Changes vs v2.1: (1) Q/qW staged global->LDS coalesced, lanes pull rows
// from LDS (was: 2KB-strided per-lane global loads, 64 lines/instr);
// (2) PV split into two d-halves (av 64->32 regs, exp recomputed) so peak
// live set ~170 VGPR — safely under the (256,2) cap, no scratch in hot loop;
// (3) partial-acc stores routed through LDS, written coalesced by all lanes.
#define BAND_STEP(WSX, WCX, WSY, WCY)                              \
    r0 += sxa * (WSX); r1 += cxa * (WCX);                          \
    r2 += sya * (WSY); r3 += cya * (WCY);                          \
    {   float tt;                                                  \
        tt = Kx * sxb - sxa; sxa = sxb; sxb = tt;                  \
        tt = Kx * cxb - cxa; cxa = cxb; cxb = tt;                  \
        tt = Ky * syb - sya; sya = syb; syb = tt;                  \
        tt = Ky * cyb - cya; cya = cyb; cyb = tt; }

__global__ __launch_bounds__(256, 2) void k_attn(
    const float* __restrict__ pos, float* __restrict__ ws)
{
    const float* q  = ws + Q_OFF;
    const float* kc = ws + KC_OFF;
    const float* v  = ws + V_OFF;
    const float* qW = ws + QW_OFF;
    float* pacc = ws + PA_OFF;
    float* pm   = ws + PM_OFF;
    float* pl   = ws + PL_OFF;

    const int c  = blockIdx.x;             // jsuper 0..7
    const int it = blockIdx.y;             // itile 0..7
    const int h  = blockIdx.z;             // head
    const int tid = threadIdx.x;
    const int w = tid >> 6, l = tid & 63;
    const int i0t = it * 64;               // block's query-row base
    const int j0 = c * 64;                 // block j-range

    __shared__ alignas(16) float Ks[64][68];
    __shared__ alignas(16) float Vs[64][68];
    __shared__ alignas(16) float Qls[64][68];
    __shared__ alignas(16) float qWls[64][68];
    __shared__ float2 posKs[64];
    __shared__ float2 posQs[64];
    __shared__ float pmL[4][64];
    __shared__ float plL[4][64];

    // ---- coalesced staging: K/V rows (j0..), Q rows (i0t..), qW rows ----
    {
        const int jj = tid >> 2, dg = (tid & 3) * 16;
        const float* sk = kc + (j0 + jj) * DINNER + h * DHEAD + dg;
        *(float4*)&Ks[jj][dg +  0] = *(const float4*)(sk);
        *(float4*)&Ks[jj][dg +  4] = *(const float4*)(sk + 4);
        *(float4*)&Ks[jj][dg +  8] = *(const float4*)(sk + 8);
        *(float4*)&Ks[jj][dg + 12] = *(const float4*)(sk + 12);
        const float* sv = v + (j0 + jj) * DINNER + h * DHEAD + dg;
        *(float4*)&Vs[jj][dg +  0] = *(const float4*)(sv);
        *(float4*)&Vs[jj][dg +  4] = *(const float4*)(sv + 4);
        *(float4*)&Vs[jj][dg +  8] = *(const float4*)(sv + 8);
        *(float4*)&Vs[jj][dg + 12] = *(const float4*)(sv + 12);
        const float* sq = q + (i0t + jj) * DINNER + h * DHEAD + dg;
        *(float4*)&Qls[jj][dg +  0] = *(const float4*)(sq);
        *(float4*)&Qls[jj][dg +  4] = *(const float4*)(sq + 4);
        *(float4*)&Qls[jj][dg +  8] = *(const float4*)(sq + 8);
        *(float4*)&Qls[jj][dg + 12] = *(const float4*)(sq + 12);
        for (int idx = tid; idx < 64 * 17; idx += 256) {
            int r = idx / 17, p4 = idx - r * 17;
            *(float4*)&qWls[r][p4 * 4] =
                *(const float4*)&qW[(i0t + r) * 544 + h * 68 + p4 * 4];
        }
        if (tid < 64) {
            posKs[tid] = *(const float2*)&pos[(j0 + tid) * 2];
            posQs[tid] = *(const float2*)&pos[(i0t + tid) * 2];
        }
    }
    __syncthreads();

    // ---- per-lane row pulls from LDS (one-time; minor bank conflicts OK) --
    float4 qv[16];
    #pragma unroll
    for (int d4 = 0; d4 < 16; ++d4) qv[d4] = *(const float4*)&Qls[l][d4 * 4];
    float4 cw[17];
    #pragma unroll
    for (int p4 = 0; p4 < 17; ++p4) cw[p4] = *(const float4*)&qWls[l][p4 * 4];
    const float2 pq = posQs[l];

    const int jb = w * 16;
    float sreg[16];
    float M = -1e30f;

    // ---- score phase: content (K broadcast) + RPE (Chebyshev) ----
    #pragma unroll
    for (int t = 0; t < 16; ++t) {
        const int jr = jb + t;
        float s0 = 0.f, s1 = 0.f, s2 = 0.f, s3 = 0.f;
        #pragma unroll
        for (int d4 = 0; d4 < 16; ++d4) {
            float4 kv = *(const float4*)&Ks[jr][d4 * 4];
            s0 += qv[d4].x * kv.x; s1 += qv[d4].y * kv.y;
            s2 += qv[d4].z * kv.z; s3 += qv[d4].w * kv.w;
        }
        float s = (s0 + s1) + (s2 + s3);

        float2 pk = posKs[jr];
        float dxr = (pk.x - pq.x) * (1.0f / 51.0f);
        float dyr = (pk.y - pq.y) * (1.0f / 51.0f);
        float dx = __fdividef(dxr, 1.0f + fabsf(dxr));
        float dy = __fdividef(dyr, 1.0f + fabsf(dyr));
        float thx = dx * PI_F, dlx = dx * (PI_F * 7.0f / 15.0f);
        float thy = dy * PI_F, dly = dy * (PI_F * 7.0f / 15.0f);
        float sxa, cxa, sxb, cxb, sya, cya, syb, cyb;
        __sincosf(thx,       &sxa, &cxa);
        __sincosf(thx + dlx, &sxb, &cxb);
        __sincosf(thy,       &sya, &cya);
        __sincosf(thy + dly, &syb, &cyb);
        float Kx = 2.0f * (cxa * cxb + sxa * sxb);   // 2*cos(dlx)
        float Ky = 2.0f * (cya * cyb + sya * syb);   // 2*cos(dly)
        float r0 = 0.f, r1 = 0.f, r2 = 0.f, r3 = 0.f;
        #pragma unroll
        for (int g = 0; g < 4; ++g) {
            float4 wsx = cw[g], wcx = cw[4 + g], wsy = cw[8 + g], wcy = cw[12 + g];
            BAND_STEP(wsx.x, wcx.x, wsy.x, wcy.x)
            BAND_STEP(wsx.y, wcx.y, wsy.y, wcy.y)
            BAND_STEP(wsx.z, wcx.z, wsy.z, wcy.z)
            BAND_STEP(wsx.w, wcx.w, wsy.w, wcy.w)
        }
        float rpe = (r0 + r1) + (r2 + r3) + dx * cw[16].x + dy * cw[16].y;
        float score = s * SCALE + rpe;
        sreg[t] = score;
        M = fmaxf(M, score);
    }

    // local sum (relative to local max M), publish per-wave stats
    float lsum = 0.f;
    #pragma unroll
    for (int t = 0; t < 16; ++t) lsum += __expf(sreg[t] - M);
    pmL[w][l] = M; plL[w][l] = lsum;
    __syncthreads();
    const float m0 = pmL[0][l], m1 = pmL[1][l], m2 = pmL[2][l], m3 = pmL[3][l];
    const float Mg = fmaxf(fmaxf(m0, m1), fmaxf(m2, m3));

    // ---- PV in two d-halves (av = 8 float4 = 32 VGPR peak) ----
    float (*Sacc)[68] = Ks;   // reuse Ks (score reads done)
    #pragma unroll
    for (int h2 = 0; h2 < 2; ++h2) {
        float4 av[8];
        #pragma unroll
        for (int d4 = 0; d4 < 8; ++d4) av[d4] = make_float4(0.f, 0.f, 0.f, 0.f);
        #pragma unroll
        for (int t = 0; t < 16; ++t) {
            float p = __expf(sreg[t] - Mg);   // global-max referenced: no rescale
            const int jr = jb + t;
            #pragma unroll
            for (int d4 = 0; d4 < 8; ++d4) {
                float4 vv = *(const float4*)&Vs[jr][(h2 * 8 + d4) * 4];
                av[d4].x += p * vv.x; av[d4].y += p * vv.y;
                av[d4].z += p * vv.z; av[d4].w += p * vv.w;
            }
        }
        // serialized 4-wave accumulation into Sacc columns of this half
        if (w == 0) {
            #pragma unroll
            for (int d4 = 0; d4 < 8; ++d4)
                *(float4*)&Sacc[l][(h2 * 8 + d4) * 4] = av[d4];
        }
        __syncthreads();
        if (w == 1) {
            #pragma unroll
            for (int d4 = 0; d4 < 8; ++d4) {
                float4 sv = *(const float4*)&Sacc[l][(h2 * 8 + d4) * 4];
                sv.x += av[d4].x; sv.y += av[d4].y; sv.z += av[d4].z; sv.w += av[d4].w;
                *(float4*)&Sacc[l][(h2 * 8 + d4) * 4] = sv;
            }
        }
        __syncthreads();
        if (w == 2) {
            #pragma unroll
            for (int d4 = 0; d4 < 8; ++d4) {
                float4 sv = *(const float4*)&Sacc[l][(h2 * 8 + d4) * 4];
                sv.x += av[d4].x; sv.y += av[d4].y; sv.z += av[d4].z; sv.w += av[d4].w;
                *(float4*)&Sacc[l][(h2 * 8 + d4) * 4] = sv;
            }
        }
        __syncthreads();
        if (w == 3) {
            #pragma unroll
            for (int d4 = 0; d4 < 8; ++d4) {
                float4 sv = *(const float4*)&Sacc[l][(h2 * 8 + d4) * 4];
                sv.x += av[d4].x; sv.y += av[d4].y; sv.z += av[d4].z; sv.w += av[d4].w;
                *(float4*)&Sacc[l][(h2 * 8 + d4) * 4] = sv;
            }
        }
        __syncthreads();
        // coalesced store of this half: 64 rows x 32 floats
        for (int idx = tid; idx < 64 * 8; idx += 256) {
            int r = idx >> 3, p4 = idx & 7;
            *(float4*)&pacc[((size_t)((h * NQ + i0t + r) * 8 + c)) * 64 + h2 * 32 + p4 * 4] =
                *(const float4*)&Sacc[r][(h2 * 8 + p4) * 4];
        }
    }

    // per-row stats (one lane per row)
    if (tid < 64) {
        float Lg = plL[0][tid] * __expf(pmL[0][tid] - Mg)
                 + plL[1][tid] * __expf(pmL[1][tid] - Mg)
                 + plL[2][tid] * __expf(pmL[2][tid] - Mg)
                 + plL[3][tid] * __expf(pmL[3][tid] - Mg);
        pm[(h * NQ + i0t + tid) * 8 + c] = Mg;
        pl[(h * NQ + i0t + tid) * 8 + c] = Lg;
    }
}

// --------------- cross-block merge of 8 partials -> inner -------------------
__global__ __launch_bounds__(256) void k_merge(float* __restrict__ ws)
{
    float* inner      = ws + IN_OFF;
    const float* pacc = ws + PA_OFF;
    const float* pm   = ws + PM_OFF;
    const float* pl   = ws + PL_OFF;

    const int g = blockIdx.x * 4 + (threadIdx.x >> 6);  // (h,i) row, 0..4095
    const int l = threadIdx.x & 63;                     // d

    float mv[8];
    #pragma unroll
    for (int cc = 0; cc < 8; ++cc) mv[cc] = pm[g * 8 + cc];
    float Mg = mv[0];
    #pragma unroll
    for (int cc = 1; cc < 8; ++cc) Mg = fmaxf(Mg, mv[cc]);
    float L = 0.f, a = 0.f;
    #pragma unroll
    for (int cc = 0; cc < 8; ++cc) {
        float e = __expf(mv[cc] - Mg);
        L += pl[g * 8 + cc] * e;
        a += pacc[(size_t)(g * 8 + cc) * 64 + l] * e;
    }
    const int h = g >> 9, i = g & 511;
    inner[i * DINNER + h * DHEAD + l] = a / L;
}

// ------------------------------------------------ K5: out = inner @ Wo + bo
__global__ __launch_bounds__(256) void k_out(
    const float* __restrict__ Wo, const float* __restrict__ bo,
    float* __restrict__ ws, float* __restrict__ outp)
{
    const float* inner = ws + IN_OFF;
    const int c0 = blockIdx.x * 32;
    const int i0 = blockIdx.y * 32;

    __shared__ alignas(16) float Xs[32][36];   // [kk][m]
    __shared__ alignas(16) float Bs[32][32];   // [kk][n]
    const int tx = threadIdx.x, ty = threadIdx.y;
    const int tid = ty * 16 + tx;

    float acc[2][2] = {};
    for (int k0 = 0; k0 < DINNER; k0 += 32) {
        {
            const int m = tid >> 3;
            const int kk0 = (tid & 7) * 4;
            float4 a4 = *(const float4*)&inner[(i0 + m) * DINNER + k0 + kk0];
            Xs[kk0 + 0][m] = a4.x; Xs[kk0 + 1][m] = a4.y;
            Xs[kk0 + 2][m] = a4.z; Xs[kk0 + 3][m] = a4.w;
        }
        {
            const int kk = tid >> 3;
            const int n0 = (tid & 7) * 4;
            *(float4*)&Bs[kk][n0] = *(const float4*)&Wo[(k0 + kk) * DMODEL + c0 + n0];
        }
        __syncthreads();
        #pragma unroll
        for (int kk = 0; kk < 32; ++kk) {
            float2 a2 = *(const float2*)&Xs[kk][ty * 2];
            float2 b2 = *(const float2*)&Bs[kk][tx * 2];
            acc[0][0] += a2.x * b2.x;
            acc[0][1] += a2.x * b2.y;
            acc[1][0] += a2.y * b2.x;
            acc[1][1] += a2.y * b2.y;
        }
        __syncthreads();
    }
    #pragma unroll
    for (int ia = 0; ia < 2; ++ia) {
        float2 o;
        o.x = acc[ia][0] + bo[c0 + tx * 2 + 0];
        o.y = acc[ia][1] + bo[c0 + tx * 2 + 1];
        *(float2*)&outp[(i0 + ty * 2 + ia) * DMODEL + c0 + tx * 2] = o;
    }
}

extern "C" void kernel_launch(void* const* d_in, const int* in_sizes, int n_in,
                              void* d_out, int out_size, void* d_ws, size_t ws_size,
                              hipStream_t stream)
{
    const float* x   = (const float*)d_in[0];
    const float* pos = (const float*)d_in[1];
    const float* Wq  = (const float*)d_in[2];
    const float* Wk  = (const float*)d_in[3];
    const float* Wv  = (const float*)d_in[4];
    const float* Wo  = (const float*)d_in[5];
    const float* bo  = (const float*)d_in[6];
    float* out = (float*)d_out;
    float* ws  = (float*)d_ws;

    k_proj<<<dim3(8, 8, 3), dim3(16, 16), 0, stream>>>(x, Wq, Wk, Wv, ws);
    k_qw<<<dim3(128), dim3(256), 0, stream>>>(Wk, ws);
    k_attn<<<dim3(8, 8, 8), dim3(256), 0, stream>>>(pos, ws);
    k_merge<<<dim3(1024), dim3(256), 0, stream>>>(ws);
    k_out<<<dim3(8, 16), dim3(16, 16), 0, stream>>>(Wo, bo, ws, out);
}

// Round 12
// 146.017 us; speedup vs baseline: 1.2375x; 1.2375x over previous
//
#include <hip/hip_runtime.h>
#include <math.h>

#define NQ      512
#define DMODEL  256
#define DINNER  512
#define NH      8
#define DHEAD   64
#define SCALE   0.125f
#define PI_F    3.14159265358979323846f

// workspace layout (float offsets)
#define Q_OFF   0           // 512*512
#define KC_OFF  262144      // 512*512
#define V_OFF   524288      // 512*512
#define QW_OFF  786432      // 512*544 (per-head blocks of 68)
#define IN_OFF  1064960     // 512*512
#define PA_OFF  1327104     // 4096*8*64 partial accs
#define PM_OFF  3424256     // 4096*8 partial maxes
#define PL_OFF  3457024     // 4096*8 partial sums
// total 3489792 floats = 14.0 MB

// ---------------------------------------------------------------- K1: q/kc/v
__global__ __launch_bounds__(256) void k_proj(
    const float* __restrict__ x, const float* __restrict__ Wq,
    const float* __restrict__ Wk, const float* __restrict__ Wv,
    float* __restrict__ ws)
{
    const int z = blockIdx.z;
    const float* W = (z == 0) ? Wq : (z == 1) ? Wk : Wv;
    float* out = ws + ((z == 0) ? Q_OFF : (z == 1) ? KC_OFF : V_OFF);

    __shared__ alignas(16) float Xs[32][68];
    __shared__ alignas(16) float Bs[32][64];

    const int tx = threadIdx.x, ty = threadIdx.y;
    const int tid = ty * 16 + tx;
    const int row0 = blockIdx.y * 64, col0 = blockIdx.x * 64;

    float acc[4][4] = {};

    for (int k0 = 0; k0 < DMODEL; k0 += 32) {
        {
            const int m = tid >> 2;
            const int kk0 = (tid & 3) * 8;
            const float* src = x + (row0 + m) * DMODEL + k0 + kk0;
            float4 a0 = *(const float4*)(src);
            float4 a1 = *(const float4*)(src + 4);
            Xs[kk0 + 0][m] = a0.x; Xs[kk0 + 1][m] = a0.y;
            Xs[kk0 + 2][m] = a0.z; Xs[kk0 + 3][m] = a0.w;
            Xs[kk0 + 4][m] = a1.x; Xs[kk0 + 5][m] = a1.y;
            Xs[kk0 + 6][m] = a1.z; Xs[kk0 + 7][m] = a1.w;
        }
        {
            const int kk = tid >> 3;
            const int n0 = (tid & 7) * 8;
            const float* src = W + (k0 + kk) * DINNER + col0 + n0;
            *(float4*)&Bs[kk][n0]     = *(const float4*)(src);
            *(float4*)&Bs[kk][n0 + 4] = *(const float4*)(src + 4);
        }
        __syncthreads();
        #pragma unroll
        for (int kk = 0; kk < 32; ++kk) {
            float4 a4 = *(const float4*)&Xs[kk][ty * 4];
            float4 b4 = *(const float4*)&Bs[kk][tx * 4];
            float a[4] = {a4.x, a4.y, a4.z, a4.w};
            float b[4] = {b4.x, b4.y, b4.z, b4.w};
            #pragma unroll
            for (int ia = 0; ia < 4; ++ia)
                #pragma unroll
                for (int ib = 0; ib < 4; ++ib)
                    acc[ia][ib] += a[ia] * b[ib];
        }
        __syncthreads();
    }
    #pragma unroll
    for (int ia = 0; ia < 4; ++ia) {
        float4 o = make_float4(acc[ia][0], acc[ia][1], acc[ia][2], acc[ia][3]);
        *(float4*)&out[(row0 + ty * 4 + ia) * DINNER + col0 + tx * 4] = o;
    }
}

// ------------------------------------------------- K1b: qW, per-head layout
// qW[i*544 + h*68 + p]; p: 0..15 sin_x, 16..31 cos_x, 32..47 sin_y,
// 48..63 cos_y, 64 dx-weight, 65 dy-weight. (SCALE folded in.)
__global__ __launch_bounds__(256) void k_qw(
    const float* __restrict__ Wk, float* __restrict__ ws)
{
    const float* q = ws + Q_OFF;
    float* qW = ws + QW_OFF;
    const int h  = blockIdx.x >> 4;          // 8 heads
    const int i0 = (blockIdx.x & 15) * 32;   // 16 row-tiles of 32

    __shared__ float WrT[64][67];            // [d][r], pad 67
    __shared__ alignas(16) float Qs[32][68]; // [m][d]
    const int tid = threadIdx.x;

    for (int idx = tid; idx < 66 * 64; idx += 256) {
        int r = idx >> 6, d = idx & 63;
        WrT[d][r] = Wk[(DMODEL + r) * DINNER + h * DHEAD + d];
    }
    for (int idx = tid; idx < 32 * 16; idx += 256) {
        int m = idx >> 4, dq = (idx & 15) * 4;
        *(float4*)&Qs[m][dq] = *(const float4*)&q[(i0 + m) * DINNER + h * DHEAD + dq];
    }
    __syncthreads();

    for (int idx = tid; idx < 32 * 66; idx += 256) {
        int m = idx / 66, r = idx - m * 66;
        float acc = 0.f;
        #pragma unroll
        for (int d0 = 0; d0 < 64; d0 += 4) {
            float4 qf = *(const float4*)&Qs[m][d0];
            acc += qf.x * WrT[d0 + 0][r] + qf.y * WrT[d0 + 1][r]
                 + qf.z * WrT[d0 + 2][r] + qf.w * WrT[d0 + 3][r];
        }
        // original r: 0..15 sinx, 16..31 cosx, 32 dx, 33..48 siny, 49..64 cosy, 65 dy
        int p = (r < 32) ? r : (r == 32) ? 64 : (r < 65) ? (r - 1) : 65;
        qW[(i0 + m) * 544 + h * 68 + p] = acc * SCALE;
    }
}

// --------- fused attention v4: v2.1 structure, launch_bounds(256,1) --------
// v3 counters confirmed massive spilling: VGPR capped at 128 while per-lane
// state needs ~240 (qv 64 + cw 68 + av 64 + sreg 16 + temps) -> 120MB scratch
// stores/launch. The (256,2) bound drives the allocator's waves/EU target.
// Fix: (256,1) -> VGPR cap 512; allocator keeps state resident.
#define BAND_STEP(WSX, WCX, WSY, WCY)                              \
    r0 += sxa * (WSX); r1 += cxa * (WCX);                          \
    r2 += sya * (WSY); r3 += cya * (WCY);                          \
    {   float tt;                                                  \
        tt = Kx * sxb - sxa; sxa = sxb; sxb = tt;                  \
        tt = Kx * cxb - cxa; cxa = cxb; cxb = tt;                  \
        tt = Ky * syb - sya; sya = syb; syb = tt;                  \
        tt = Ky * cyb - cya; cya = cyb; cyb = tt; }

__global__ __launch_bounds__(256, 1) void k_attn(
    const float* __restrict__ pos, float* __restrict__ ws)
{
    const float* q  = ws + Q_OFF;
    const float* kc = ws + KC_OFF;
    const float* v  = ws + V_OFF;
    const float* qW = ws + QW_OFF;
    float* pacc = ws + PA_OFF;
    float* pm   = ws + PM_OFF;
    float* pl   = ws + PL_OFF;

    const int c  = blockIdx.x;             // jsuper 0..7
    const int it = blockIdx.y;             // itile 0..7
    const int h  = blockIdx.z;             // head
    const int tid = threadIdx.x;
    const int w = tid >> 6, l = tid & 63;
    const int i = it * 64 + l;             // this lane's query row
    const int j0 = c * 64;                 // block j-range

    __shared__ alignas(16) float Ks[64][68];
    __shared__ alignas(16) float Vs[64][68];
    __shared__ float2 posKs[64];
    __shared__ float pmL[4][64];
    __shared__ float plL[4][64];

    // stage K/V rows j0..j0+63 (coalesced global, once per block)
    {
        const int jj = tid >> 2, dg = (tid & 3) * 16;
        const float* sk = kc + (j0 + jj) * DINNER + h * DHEAD + dg;
        *(float4*)&Ks[jj][dg +  0] = *(const float4*)(sk);
        *(float4*)&Ks[jj][dg +  4] = *(const float4*)(sk + 4);
        *(float4*)&Ks[jj][dg +  8] = *(const float4*)(sk + 8);
        *(float4*)&Ks[jj][dg + 12] = *(const float4*)(sk + 12);
        const float* sv = v + (j0 + jj) * DINNER + h * DHEAD + dg;
        *(float4*)&Vs[jj][dg +  0] = *(const float4*)(sv);
        *(float4*)&Vs[jj][dg +  4] = *(const float4*)(sv + 4);
        *(float4*)&Vs[jj][dg +  8] = *(const float4*)(sv + 8);
        *(float4*)&Vs[jj][dg + 12] = *(const float4*)(sv + 12);
        if (tid < 64) posKs[tid] = *(const float2*)&pos[(j0 + tid) * 2];
    }

    // per-lane register loads (own row; once per kernel)
    float4 qv[16];
    const float* qrow = q + i * DINNER + h * DHEAD;
    #pragma unroll
    for (int d4 = 0; d4 < 16; ++d4) qv[d4] = *(const float4*)(qrow + d4 * 4);
    float4 cw[17];
    const float* qwrow = qW + i * 544 + h * 68;
    #pragma unroll
    for (int p4 = 0; p4 < 17; ++p4) cw[p4] = *(const float4*)(qwrow + p4 * 4);
    const float2 pq = *(const float2*)&pos[i * 2];

    __syncthreads();

    const int jb = w * 16;
    float sreg[16];
    float M = -1e30f;

    #pragma unroll
    for (int t = 0; t < 16; ++t) {
        const int jr = jb + t;
        // content dot: K row broadcast (uniform addr), Q in regs
        float s0 = 0.f, s1 = 0.f, s2 = 0.f, s3 = 0.f;
        #pragma unroll
        for (int d4 = 0; d4 < 16; ++d4) {
            float4 kv = *(const float4*)&Ks[jr][d4 * 4];
            s0 += qv[d4].x * kv.x; s1 += qv[d4].y * kv.y;
            s2 += qv[d4].z * kv.z; s3 += qv[d4].w * kv.w;
        }
        float s = (s0 + s1) + (s2 + s3);

        // RPE: per-lane features (Chebyshev ladder), coeffs in regs
        float2 pk = posKs[jr];
        float dxr = (pk.x - pq.x) * (1.0f / 51.0f);
        float dyr = (pk.y - pq.y) * (1.0f / 51.0f);
        float dx = __fdividef(dxr, 1.0f + fabsf(dxr));
        float dy = __fdividef(dyr, 1.0f + fabsf(dyr));
        float thx = dx * PI_F, dlx = dx * (PI_F * 7.0f / 15.0f);
        float thy = dy * PI_F, dly = dy * (PI_F * 7.0f / 15.0f);
        float sxa, cxa, sxb, cxb, sya, cya, syb, cyb;
        __sincosf(thx,       &sxa, &cxa);
        __sincosf(thx + dlx, &sxb, &cxb);
        __sincosf(thy,       &sya, &cya);
        __sincosf(thy + dly, &syb, &cyb);
        float Kx = 2.0f * (cxa * cxb + sxa * sxb);   // 2*cos(dlx)
        float Ky = 2.0f * (cya * cyb + sya * syb);   // 2*cos(dly)
        float r0 = 0.f, r1 = 0.f, r2 = 0.f, r3 = 0.f;
        #pragma unroll
        for (int g = 0; g < 4; ++g) {
            float4 wsx = cw[g], wcx = cw[4 + g], wsy = cw[8 + g], wcy = cw[12 + g];
            BAND_STEP(wsx.x, wcx.x, wsy.x, wcy.x)
            BAND_STEP(wsx.y, wcx.y, wsy.y, wcy.y)
            BAND_STEP(wsx.z, wcx.z, wsy.z, wcy.z)
            BAND_STEP(wsx.w, wcx.w, wsy.w, wcy.w)
        }
        float rpe = (r0 + r1) + (r2 + r3) + dx * cw[16].x + dy * cw[16].y;
        float score = s * SCALE + rpe;
        sreg[t] = score;
        M = fmaxf(M, score);
    }

    // single-pass softmax over this wave's 16-j chunk + PV accumulate
    float4 av[16];
    #pragma unroll
    for (int d4 = 0; d4 < 16; ++d4) av[d4] = make_float4(0.f, 0.f, 0.f, 0.f);
    float lsum = 0.f;
    #pragma unroll
    for (int t = 0; t < 16; ++t) {
        float p = __expf(sreg[t] - M);
        lsum += p;
        const int jr = jb + t;
        #pragma unroll
        for (int d4 = 0; d4 < 16; ++d4) {
            float4 vv = *(const float4*)&Vs[jr][d4 * 4];
            av[d4].x += p * vv.x; av[d4].y += p * vv.y;
            av[d4].z += p * vv.z; av[d4].w += p * vv.w;
        }
    }

    // ---- intra-block merge of 4 waves (same (h,i), different j-quarters) ----
    pmL[w][l] = M; plL[w][l] = lsum;
    __syncthreads();
    float m0 = pmL[0][l], m1 = pmL[1][l], m2 = pmL[2][l], m3 = pmL[3][l];
    float Mg = fmaxf(fmaxf(m0, m1), fmaxf(m2, m3));
    float e = __expf(M - Mg);
    #pragma unroll
    for (int d4 = 0; d4 < 16; ++d4) {
        av[d4].x *= e; av[d4].y *= e; av[d4].z *= e; av[d4].w *= e;
    }
    float (*Sacc)[68] = Ks;   // reuse Ks (all reads done)
    if (w == 0) {
        #pragma unroll
        for (int d4 = 0; d4 < 16; ++d4) *(float4*)&Sacc[l][d4 * 4] = av[d4];
    }
    __syncthreads();
    if (w == 1) {
        #pragma unroll
        for (int d4 = 0; d4 < 16; ++d4) {
            float4 sv = *(const float4*)&Sacc[l][d4 * 4];
            sv.x += av[d4].x; sv.y += av[d4].y; sv.z += av[d4].z; sv.w += av[d4].w;
            *(float4*)&Sacc[l][d4 * 4] = sv;
        }
    }
    __syncthreads();
    if (w == 2) {
        #pragma unroll
        for (int d4 = 0; d4 < 16; ++d4) {
            float4 sv = *(const float4*)&Sacc[l][d4 * 4];
            sv.x += av[d4].x; sv.y += av[d4].y; sv.z += av[d4].z; sv.w += av[d4].w;
            *(float4*)&Sacc[l][d4 * 4] = sv;
        }
    }
    __syncthreads();
    if (w == 3) {
        float Lg = plL[0][l] * __expf(m0 - Mg) + plL[1][l] * __expf(m1 - Mg)
                 + plL[2][l] * __expf(m2 - Mg) + plL[3][l] * __expf(m3 - Mg);
        float* prow = pacc + ((size_t)((h * NQ + i) * 8 + c)) * 64;
        #pragma unroll
        for (int d4 = 0; d4 < 16; ++d4) {
            float4 sv = *(const float4*)&Sacc[l][d4 * 4];
            sv.x += av[d4].x; sv.y += av[d4].y; sv.z += av[d4].z; sv.w += av[d4].w;
            *(float4*)&prow[d4 * 4] = sv;
        }
        pm[(h * NQ + i) * 8 + c] = Mg;
        pl[(h * NQ + i) * 8 + c] = Lg;
    }
}

// --------------- cross-block merge of 8 partials -> inner -------------------
__global__ __launch_bounds__(256) void k_merge(float* __restrict__ ws)
{
    float* inner      = ws + IN_OFF;
    const float* pacc = ws + PA_OFF;
    const float* pm   = ws + PM_OFF;
    const float* pl   = ws + PL_OFF;

    const int g = blockIdx.x * 4 + (threadIdx.x >> 6);  // (h,i) row, 0..4095
    const int l = threadIdx.x & 63;                     // d

    float mv[8];
    #pragma unroll
    for (int cc = 0; cc < 8; ++cc) mv[cc] = pm[g * 8 + cc];
    float Mg = mv[0];
    #pragma unroll
    for (int cc = 1; cc < 8; ++cc) Mg = fmaxf(Mg, mv[cc]);
    float L = 0.f, a = 0.f;
    #pragma unroll
    for (int cc = 0; cc < 8; ++cc) {
        float e = __expf(mv[cc] - Mg);
        L += pl[g * 8 + cc] * e;
        a += pacc[(size_t)(g * 8 + cc) * 64 + l] * e;
    }
    const int h = g >> 9, i = g & 511;
    inner[i * DINNER + h * DHEAD + l] = a / L;
}

// ------------------------------------------------ K5: out = inner @ Wo + bo
__global__ __launch_bounds__(256) void k_out(
    const float* __restrict__ Wo, const float* __restrict__ bo,
    float* __restrict__ ws, float* __restrict__ outp)
{
    const float* inner = ws + IN_OFF;
    const int c0 = blockIdx.x * 32;
    const int i0 = blockIdx.y * 32;

    __shared__ alignas(16) float Xs[32][36];   // [kk][m]
    __shared__ alignas(16) float Bs[32][32];   // [kk][n]
    const int tx = threadIdx.x, ty = threadIdx.y;
    const int tid = ty * 16 + tx;

    float acc[2][2] = {};
    for (int k0 = 0; k0 < DINNER; k0 += 32) {
        {
            const int m = tid >> 3;
            const int kk0 = (tid & 7) * 4;
            float4 a4 = *(const float4*)&inner[(i0 + m) * DINNER + k0 + kk0];
            Xs[kk0 + 0][m] = a4.x; Xs[kk0 + 1][m] = a4.y;
            Xs[kk0 + 2][m] = a4.z; Xs[kk0 + 3][m] = a4.w;
        }
        {
            const int kk = tid >> 3;
            const int n0 = (tid & 7) * 4;
            *(float4*)&Bs[kk][n0] = *(const float4*)&Wo[(k0 + kk) * DMODEL + c0 + n0];
        }
        __syncthreads();
        #pragma unroll
        for (int kk = 0; kk < 32; ++kk) {
            float2 a2 = *(const float2*)&Xs[kk][ty * 2];
            float2 b2 = *(const float2*)&Bs[kk][tx * 2];
            acc[0][0] += a2.x * b2.x;
            acc[0][1] += a2.x * b2.y;
            acc[1][0] += a2.y * b2.x;
            acc[1][1] += a2.y * b2.y;
        }
        __syncthreads();
    }
    #pragma unroll
    for (int ia = 0; ia < 2; ++ia) {
        float2 o;
        o.x = acc[ia][0] + bo[c0 + tx * 2 + 0];
        o.y = acc[ia][1] + bo[c0 + tx * 2 + 1];
        *(float2*)&outp[(i0 + ty * 2 + ia) * DMODEL + c0 + tx * 2] = o;
    }
}

extern "C" void kernel_launch(void* const* d_in, const int* in_sizes, int n_in,
                              void* d_out, int out_size, void* d_ws, size_t ws_size,
                              hipStream_t stream)
{
    const float* x   = (const float*)d_in[0];
    const float* pos = (const float*)d_in[1];
    const float* Wq  = (const float*)d_in[2];
    const float* Wk  = (const float*)d_in[3];
    const float* Wv  = (const float*)d_in[4];
    const float* Wo  = (const float*)d_in[5];
    const float* bo  = (const float*)d_in[6];
    float* out = (float*)d_out;
    float* ws  = (float*)d_ws;

    k_proj<<<dim3(8, 8, 3), dim3(16, 16), 0, stream>>>(x, Wq, Wk, Wv, ws);
    k_qw<<<dim3(128), dim3(256), 0, stream>>>(Wk, ws);
    k_attn<<<dim3(8, 8, 8), dim3(256), 0, stream>>>(pos, ws);
    k_merge<<<dim3(1024), dim3(256), 0, stream>>>(ws);
    k_out<<<dim3(8, 16), dim3(16, 16), 0, stream>>>(Wo, bo, ws, out);
}